// Round 3
// baseline (90.346 us; speedup 1.0000x reference)
//
#include <hip/hip_runtime.h>
#include <hip/hip_bf16.h>
#include <cstdint>

#define SIGMA 0.01f

constexpr int D1 = 3072;
constexpr int D2 = 2048;
constexpr int D3 = 1024;

typedef __bf16 bf16x8 __attribute__((ext_vector_type(8)));
typedef float f32x4 __attribute__((ext_vector_type(4)));

#define GLOAD16(gp, lp) \
  __builtin_amdgcn_global_load_lds((const __attribute__((address_space(1))) void*)(gp), \
                                   (__attribute__((address_space(3))) void*)(lp), 16, 0, 0)

// ---------- K1: bias add + 2x2 avgpool + per-block partial sum(pooled^2) ----------
__global__ void pool_kernel(const float* __restrict__ x, const float* __restrict__ bias,
                            float* __restrict__ pooled, float* __restrict__ Spart) {
  int idx = blockIdx.x * 256 + threadIdx.x;   // [0, 4*3072)
  int b = idx / D1;
  int r = idx % D1;
  int c = r >> 10;
  int oh = (r >> 5) & 31;
  int ow = r & 31;
  int xb = ((b * 3 + c) * 64 + oh * 2) * 64 + ow * 2;
  int bb = (c * 64 + oh * 2) * 64 + ow * 2;
  float v = 0.25f * ((x[xb] + bias[bb]) + (x[xb + 1] + bias[bb + 1]) +
                     (x[xb + 64] + bias[bb + 64]) + (x[xb + 65] + bias[bb + 65]));
  pooled[idx] = v;
  float s = v * v;
  #pragma unroll
  for (int off = 32; off; off >>= 1) s += __shfl_down(s, off, 64);
  __shared__ float wsum[4];
  if ((threadIdx.x & 63) == 0) wsum[threadIdx.x >> 6] = s;
  __syncthreads();
  if (threadIdx.x == 0) Spart[blockIdx.x] = wsum[0] + wsum[1] + wsum[2] + wsum[3];
}

// ---------- K2: mu=pooled@W1^T fused with activation moments; Pp1 partials ----------
__global__ void lin1_kernel(const float* __restrict__ pooled, const float* __restrict__ W1,
                            const float* __restrict__ Spart, const float* __restrict__ g1p,
                            float* __restrict__ musp, float* __restrict__ dscale,
                            float* __restrict__ m2b, float* __restrict__ Pp1) {
  int o = blockIdx.x, tid = threadIdx.x;
  const float4* wrow = (const float4*)(W1 + (size_t)o * D1);
  const float4* p4 = (const float4*)pooled;
  float acc[4] = {0, 0, 0, 0}, pab[4] = {0, 0, 0, 0};
  #pragma unroll
  for (int it = 0; it < 3; it++) {
    int i4 = tid + it * 256;
    float4 w = wrow[i4];
    float ax = fabsf(w.x), ay = fabsf(w.y), az = fabsf(w.z), aw2 = fabsf(w.w);
    #pragma unroll
    for (int b = 0; b < 4; b++) {
      float4 p = p4[b * 768 + i4];
      acc[b] += w.x * p.x + w.y * p.y + w.z * p.z + w.w * p.w;
      pab[b] += ax * p.x * p.x + ay * p.y * p.y + az * p.z * p.z + aw2 * p.w * p.w;
    }
  }
  __shared__ float red[8][4];
  #pragma unroll
  for (int v = 0; v < 8; v++) {
    float s = (v < 4) ? acc[v] : pab[v - 4];
    #pragma unroll
    for (int off = 32; off; off >>= 1) s += __shfl_down(s, off, 64);
    if ((tid & 63) == 0) red[v][tid >> 6] = s;
  }
  __syncthreads();
  if (tid < 8) {
    float s = red[tid][0] + red[tid][1] + red[tid][2] + red[tid][3];
    if (tid < 4) {
      int b = tid;
      float ss = 0.f;
      #pragma unroll
      for (int i = 0; i < 12; i++) ss += Spart[b * 12 + i];
      float c1 = g1p[0];
      float vn1 = 2.0f * (SIGMA / c1) * (SIGMA / c1) * ss;
      float d = 1.0f / (1.0f + expf(-s));
      float sp = fmaxf(s, 0.f) + log1pf(expf(-fabsf(s)));
      musp[b * D2 + o] = sp;
      dscale[b * D2 + o] = sqrtf(vn1) * d;
      m2b[b * D2 + o] = sp * sp + vn1 * d * d;
    } else {
      Pp1[(size_t)(tid - 4) * D2 + o] = s;
    }
  }
}

// ---------- K3: E = bf16(W2 * dscale); mu2 = musp @ W2^T; Pp2 partials ----------
__global__ void lin2_prep_kernel(const float* __restrict__ W2, const float* __restrict__ musp,
                                 const float* __restrict__ dscale, const float* __restrict__ m2b,
                                 __bf16* __restrict__ E, float* __restrict__ mu2,
                                 float* __restrict__ Pp2) {
  int o = blockIdx.x, tid = threadIdx.x;
  const float* wrow = W2 + (size_t)o * D2;
  int j0 = tid * 8;
  float w[8];
  *(float4*)&w[0] = *(const float4*)(wrow + j0);
  *(float4*)&w[4] = *(const float4*)(wrow + j0 + 4);
  float acc[4], pab[4];
  #pragma unroll
  for (int b = 0; b < 4; b++) {
    const float* ms = musp + b * D2 + j0;
    const float* dsc = dscale + b * D2 + j0;
    const float* mb = m2b + b * D2 + j0;
    bf16x8 ev;
    float a = 0.f, p = 0.f;
    #pragma unroll
    for (int jj = 0; jj < 8; jj++) {
      ev[jj] = (__bf16)(w[jj] * dsc[jj]);
      a += w[jj] * ms[jj];
      p += fabsf(w[jj]) * mb[jj];
    }
    *(bf16x8*)(E + ((size_t)b * D3 + o) * D2 + j0) = ev;
    acc[b] = a;
    pab[b] = p;
  }
  __shared__ float red[8][4];
  #pragma unroll
  for (int v = 0; v < 8; v++) {
    float s = (v < 4) ? acc[v] : pab[v - 4];
    #pragma unroll
    for (int off = 32; off; off >>= 1) s += __shfl_down(s, off, 64);
    if ((tid & 63) == 0) red[v][tid >> 6] = s;
  }
  __syncthreads();
  if (tid < 8) {
    float s = red[tid][0] + red[tid][1] + red[tid][2] + red[tid][3];
    if (tid < 4) mu2[tid * D3 + o] = s;
    else Pp2[(size_t)(tid - 4) * D3 + o] = s;
  }
}

// ---------- K4: gamma2[b] = E_b E_b^T + vn2 I ; P_tot finalize (blocks 0..3) ----------
// LDS layout: 8 regions of 1024B per operand buffer; region = rowblock*2 + ksub;
// slot s (=lane) in region holds A[rb*16 + (s&15)][k0 + ksub*32 + (s>>4)*8 .. +7].
// Fragment ds_read_b128 = region_base + lane*16 -> contiguous 1024B wave read, 0 conflicts.
__global__ __launch_bounds__(256, 4) void gamma2_gemm(const __bf16* __restrict__ E,
                                                      const float* __restrict__ m2b,
                                                      const float* __restrict__ Pp1,
                                                      const float* __restrict__ Pp2,
                                                      const float* __restrict__ g1p,
                                                      const float* __restrict__ g2p,
                                                      float* __restrict__ gamma2,
                                                      float* __restrict__ Ptot) {
  int bid = blockIdx.x, tid = threadIdx.x;
  int wid = tid >> 6, lane = tid & 63;
  int wr = wid >> 1, wc = wid & 1;
  float c2 = g2p[0];

  // XCD-pinned decode: 8 XCDs, batch b = xcd>>1; E_b (4MB) fits one XCD L2.
  int xcd = bid & 7, r = bid >> 3;          // r in [0,128)
  int b = xcd >> 1;
  int t = r * 2 + (xcd & 1);                // [0,256)
  int tm = t >> 4, tn = t & 15;

  __shared__ __bf16 As[4096], Bs[4096];
  __shared__ float vred[4], pred1[4], pred2[4];
  __shared__ float vn2sh;

  // vn2 = 2*(sigma/c2)^2 * sum_j m2b[b][j]
  {
    float s = 0.f;
    #pragma unroll
    for (int i = 0; i < 8; i++) s += m2b[b * D2 + tid + i * 256];
    #pragma unroll
    for (int off = 32; off; off >>= 1) s += __shfl_down(s, off, 64);
    if (lane == 0) vred[wid] = s;
  }
  // blocks 0..3: finalize P_tot[bid]
  if (bid < 4) {
    float p1s = 0.f, p2s = 0.f;
    #pragma unroll
    for (int i = 0; i < 8; i++) p1s += Pp1[(size_t)bid * D2 + tid + i * 256];
    #pragma unroll
    for (int i = 0; i < 4; i++) p2s += Pp2[(size_t)bid * D3 + tid + i * 256];
    #pragma unroll
    for (int off = 32; off; off >>= 1) {
      p1s += __shfl_down(p1s, off, 64);
      p2s += __shfl_down(p2s, off, 64);
    }
    if (lane == 0) { pred1[wid] = p1s; pred2[wid] = p2s; }
  }
  __syncthreads();
  if (tid == 0) {
    vn2sh = 2.0f * (SIGMA / c2) * (SIGMA / c2) * (vred[0] + vred[1] + vred[2] + vred[3]);
    if (bid < 4)
      Ptot[bid] = g1p[0] * (pred1[0] + pred1[1] + pred1[2] + pred1[3]) +
                  c2 * (pred2[0] + pred2[1] + pred2[2] + pred2[3]);
  }

  // staging addresses: wave wid stages region wid (call 0) and wid+4 (call 1)
  int rb = wid >> 1, ks = wid & 1;
  int srow = rb * 16 + (lane & 15);
  int skof = ks * 32 + ((lane >> 4) << 3);
  const __bf16* Eb = E + (size_t)b * D3 * D2;
  const __bf16* gA = Eb + (size_t)(tm * 64 + srow) * D2 + skof;
  const __bf16* gB = Eb + (size_t)(tn * 64 + srow) * D2 + skof;
  char* AsB = (char*)As;
  char* BsB = (char*)Bs;
  unsigned dstA = (unsigned)wid * 1024u;    // HW adds lane*16

  unsigned lo = (unsigned)lane * 16u;
  unsigned a0base = (unsigned)(wr * 4) * 1024u + lo;        // + ks2*1024
  unsigned a1base = (unsigned)(wr * 4 + 2) * 1024u + lo;
  unsigned b0base = (unsigned)(wc * 4) * 1024u + lo;
  unsigned b1base = (unsigned)(wc * 4 + 2) * 1024u + lo;

  f32x4 acc[2][2] = {};

  for (int k0 = 0; k0 < D2; k0 += 64) {
    GLOAD16(gA + k0,           AsB + dstA);
    GLOAD16(gA + k0 + 32 * D2, AsB + 4096 + dstA);
    GLOAD16(gB + k0,           BsB + dstA);
    GLOAD16(gB + k0 + 32 * D2, BsB + 4096 + dstA);
    __syncthreads();
    #pragma unroll
    for (int ks2 = 0; ks2 < 2; ks2++) {
      unsigned kso = (unsigned)ks2 << 10;
      bf16x8 a0 = *(const bf16x8*)(AsB + a0base + kso);
      bf16x8 a1 = *(const bf16x8*)(AsB + a1base + kso);
      bf16x8 b0 = *(const bf16x8*)(BsB + b0base + kso);
      bf16x8 b1 = *(const bf16x8*)(BsB + b1base + kso);
      acc[0][0] = __builtin_amdgcn_mfma_f32_16x16x32_bf16(a0, b0, acc[0][0], 0, 0, 0);
      acc[0][1] = __builtin_amdgcn_mfma_f32_16x16x32_bf16(a0, b1, acc[0][1], 0, 0, 0);
      acc[1][0] = __builtin_amdgcn_mfma_f32_16x16x32_bf16(a1, b0, acc[1][0], 0, 0, 0);
      acc[1][1] = __builtin_amdgcn_mfma_f32_16x16x32_bf16(a1, b1, acc[1][1], 0, 0, 0);
    }
    __syncthreads();
  }

  float vn2 = vn2sh;
  float* outb = gamma2 + (size_t)b * D3 * D3;
  int fr = lane & 15, kg = lane >> 4;
  int row0 = tm * 64 + wr * 32 + kg * 4;
  int col0 = tn * 64 + wc * 32 + fr;
  #pragma unroll
  for (int mi = 0; mi < 2; mi++)
    #pragma unroll
    for (int ni = 0; ni < 2; ni++)
      #pragma unroll
      for (int rg = 0; rg < 4; rg++) {
        int row = row0 + mi * 16 + rg;
        int cc = col0 + ni * 16;
        float v = acc[mi][ni][rg];
        if (row == cc) v += vn2;
        outb[(size_t)row * D3 + cc] = v;
      }
}

extern "C" void kernel_launch(void* const* d_in, const int* in_sizes, int n_in,
                              void* d_out, int out_size, void* d_ws, size_t ws_size,
                              hipStream_t stream) {
  (void)in_sizes; (void)n_in; (void)out_size; (void)ws_size;
  const float* x    = (const float*)d_in[0];
  const float* bias = (const float*)d_in[1];
  const float* W1   = (const float*)d_in[2];
  const float* W2   = (const float*)d_in[3];
  const float* g1   = (const float*)d_in[4];
  const float* g2   = (const float*)d_in[5];
  float* out = (float*)d_out;

  float* ws     = (float*)d_ws;
  float* pooled = ws;                    // 4*3072
  float* musp   = pooled + 4 * D1;       // 4*2048
  float* dscale = musp + 4 * D2;         // 4*2048
  float* m2b    = dscale + 4 * D2;       // 4*2048
  float* Pp1    = m2b + 4 * D2;          // 4*2048
  float* Pp2    = Pp1 + 4 * D2;          // 4*1024
  float* Spart  = Pp2 + 4 * D3;          // 48
  size_t used = (size_t)(4 * D1 + 4 * 4 * D2 + 4 * D3 + 64) * 4;
  size_t eoff = (used + 255) / 256 * 256;
  __bf16* E = (__bf16*)((char*)d_ws + eoff);   // 4*1024*2048 bf16 = 16 MiB

  pool_kernel<<<48, 256, 0, stream>>>(x, bias, pooled, Spart);
  lin1_kernel<<<2048, 256, 0, stream>>>(pooled, W1, Spart, g1, musp, dscale, m2b, Pp1);
  lin2_prep_kernel<<<1024, 256, 0, stream>>>(W2, musp, dscale, m2b, E, out, Pp2);
  gamma2_gemm<<<1024, 256, 0, stream>>>(E, m2b, Pp1, Pp2, g1, g2, out + 4 * D3,
                                        out + 4 * D3 + (size_t)4 * D3 * D3);
}

// Round 4
// 57.987 us; speedup vs baseline: 1.5580x; 1.5580x over previous
//
#include <hip/hip_runtime.h>
#include <hip/hip_bf16.h>
#include <cstdint>

#define SIGMA 0.01f

constexpr int D1 = 3072;
constexpr int D2 = 2048;
constexpr int D3 = 1024;

typedef __bf16 bf16x8 __attribute__((ext_vector_type(8)));
typedef float f32x4 __attribute__((ext_vector_type(4)));

#define GLOAD16(gp, lp) \
  __builtin_amdgcn_global_load_lds((const __attribute__((address_space(1))) void*)(gp), \
                                   (__attribute__((address_space(3))) void*)(lp), 16, 0, 0)

// ---------- K1: bias add + 2x2 avgpool + per-block partial sum(pooled^2) ----------
__global__ void pool_kernel(const float* __restrict__ x, const float* __restrict__ bias,
                            float* __restrict__ pooled, float* __restrict__ Spart) {
  int idx = blockIdx.x * 256 + threadIdx.x;   // [0, 4*3072)
  int b = idx / D1;
  int r = idx % D1;
  int c = r >> 10;
  int oh = (r >> 5) & 31;
  int ow = r & 31;
  int xb = ((b * 3 + c) * 64 + oh * 2) * 64 + ow * 2;
  int bb = (c * 64 + oh * 2) * 64 + ow * 2;
  float v = 0.25f * ((x[xb] + bias[bb]) + (x[xb + 1] + bias[bb + 1]) +
                     (x[xb + 64] + bias[bb + 64]) + (x[xb + 65] + bias[bb + 65]));
  pooled[idx] = v;
  float s = v * v;
  #pragma unroll
  for (int off = 32; off; off >>= 1) s += __shfl_down(s, off, 64);
  __shared__ float wsum[4];
  if ((threadIdx.x & 63) == 0) wsum[threadIdx.x >> 6] = s;
  __syncthreads();
  if (threadIdx.x == 0) Spart[blockIdx.x] = wsum[0] + wsum[1] + wsum[2] + wsum[3];
}

// ---------- K2: mu=pooled@W1^T fused with activation moments; Pp1 partials ----------
__global__ void lin1_kernel(const float* __restrict__ pooled, const float* __restrict__ W1,
                            const float* __restrict__ Spart, const float* __restrict__ g1p,
                            float* __restrict__ musp, float* __restrict__ dscale,
                            float* __restrict__ m2b, float* __restrict__ Pp1) {
  int o = blockIdx.x, tid = threadIdx.x;
  const float4* wrow = (const float4*)(W1 + (size_t)o * D1);
  const float4* p4 = (const float4*)pooled;
  float acc[4] = {0, 0, 0, 0}, pab[4] = {0, 0, 0, 0};
  #pragma unroll
  for (int it = 0; it < 3; it++) {
    int i4 = tid + it * 256;
    float4 w = wrow[i4];
    float ax = fabsf(w.x), ay = fabsf(w.y), az = fabsf(w.z), aw2 = fabsf(w.w);
    #pragma unroll
    for (int b = 0; b < 4; b++) {
      float4 p = p4[b * 768 + i4];
      acc[b] += w.x * p.x + w.y * p.y + w.z * p.z + w.w * p.w;
      pab[b] += ax * p.x * p.x + ay * p.y * p.y + az * p.z * p.z + aw2 * p.w * p.w;
    }
  }
  __shared__ float red[8][4];
  #pragma unroll
  for (int v = 0; v < 8; v++) {
    float s = (v < 4) ? acc[v] : pab[v - 4];
    #pragma unroll
    for (int off = 32; off; off >>= 1) s += __shfl_down(s, off, 64);
    if ((tid & 63) == 0) red[v][tid >> 6] = s;
  }
  __syncthreads();
  if (tid < 8) {
    float s = red[tid][0] + red[tid][1] + red[tid][2] + red[tid][3];
    if (tid < 4) {
      int b = tid;
      float ss = 0.f;
      #pragma unroll
      for (int i = 0; i < 12; i++) ss += Spart[b * 12 + i];
      float c1 = g1p[0];
      float vn1 = 2.0f * (SIGMA / c1) * (SIGMA / c1) * ss;
      float d = 1.0f / (1.0f + expf(-s));
      float sp = fmaxf(s, 0.f) + log1pf(expf(-fabsf(s)));
      musp[b * D2 + o] = sp;
      dscale[b * D2 + o] = sqrtf(vn1) * d;
      m2b[b * D2 + o] = sp * sp + vn1 * d * d;
    } else {
      Pp1[(size_t)(tid - 4) * D2 + o] = s;
    }
  }
}

// ---------- K3: E = bf16(W2 * dscale); mu2 = musp @ W2^T; Pp2 partials ----------
__global__ void lin2_prep_kernel(const float* __restrict__ W2, const float* __restrict__ musp,
                                 const float* __restrict__ dscale, const float* __restrict__ m2b,
                                 __bf16* __restrict__ E, float* __restrict__ mu2,
                                 float* __restrict__ Pp2) {
  int o = blockIdx.x, tid = threadIdx.x;
  const float* wrow = W2 + (size_t)o * D2;
  int j0 = tid * 8;
  float w[8];
  *(float4*)&w[0] = *(const float4*)(wrow + j0);
  *(float4*)&w[4] = *(const float4*)(wrow + j0 + 4);
  float acc[4], pab[4];
  #pragma unroll
  for (int b = 0; b < 4; b++) {
    const float* ms = musp + b * D2 + j0;
    const float* dsc = dscale + b * D2 + j0;
    const float* mb = m2b + b * D2 + j0;
    bf16x8 ev;
    float a = 0.f, p = 0.f;
    #pragma unroll
    for (int jj = 0; jj < 8; jj++) {
      ev[jj] = (__bf16)(w[jj] * dsc[jj]);
      a += w[jj] * ms[jj];
      p += fabsf(w[jj]) * mb[jj];
    }
    *(bf16x8*)(E + ((size_t)b * D3 + o) * D2 + j0) = ev;
    acc[b] = a;
    pab[b] = p;
  }
  __shared__ float red[8][4];
  #pragma unroll
  for (int v = 0; v < 8; v++) {
    float s = (v < 4) ? acc[v] : pab[v - 4];
    #pragma unroll
    for (int off = 32; off; off >>= 1) s += __shfl_down(s, off, 64);
    if ((tid & 63) == 0) red[v][tid >> 6] = s;
  }
  __syncthreads();
  if (tid < 8) {
    float s = red[tid][0] + red[tid][1] + red[tid][2] + red[tid][3];
    if (tid < 4) mu2[tid * D3 + o] = s;
    else Pp2[(size_t)(tid - 4) * D3 + o] = s;
  }
}

// ---------- K4: per-batch scalars: vn2[b], Ptot[b] ----------
__global__ void scalars_kernel(const float* __restrict__ m2b, const float* __restrict__ Pp1,
                               const float* __restrict__ Pp2, const float* __restrict__ g1p,
                               const float* __restrict__ g2p, float* __restrict__ vn2v,
                               float* __restrict__ Ptot) {
  int b = blockIdx.x, tid = threadIdx.x;
  float sm = 0.f, s1 = 0.f, s2 = 0.f;
  #pragma unroll
  for (int i = 0; i < 8; i++) {
    sm += m2b[(size_t)b * D2 + tid + i * 256];
    s1 += Pp1[(size_t)b * D2 + tid + i * 256];
  }
  #pragma unroll
  for (int i = 0; i < 4; i++) s2 += Pp2[(size_t)b * D3 + tid + i * 256];
  __shared__ float red[3][4];
  #pragma unroll
  for (int v = 0; v < 3; v++) {
    float s = (v == 0) ? sm : (v == 1) ? s1 : s2;
    #pragma unroll
    for (int off = 32; off; off >>= 1) s += __shfl_down(s, off, 64);
    if ((tid & 63) == 0) red[v][tid >> 6] = s;
  }
  __syncthreads();
  if (tid == 0) {
    float c2 = g2p[0];
    float smt = red[0][0] + red[0][1] + red[0][2] + red[0][3];
    float s1t = red[1][0] + red[1][1] + red[1][2] + red[1][3];
    float s2t = red[2][0] + red[2][1] + red[2][2] + red[2][3];
    vn2v[b] = 2.0f * (SIGMA / c2) * (SIGMA / c2) * smt;
    Ptot[b] = g1p[0] * s1t + c2 * s2t;
  }
}

// ---------- K5: gamma2[b] = E_b E_b^T + vn2 I  (64x64, dbuf LDS, 2-phase prefetch) ----------
// LDS per 8KB buffer: region r (1KB) holds rows [(r>>1)*16, +16) x k-half (r&1)*32.
// Slot s in region: row (r>>1)*16 + (s>>2), 16B k-chunk (s&3).  Stage: wave wid does
// regions {wid, wid+4}; lane l -> slot l -> row +(l>>2), chunk l&3 (64B-contig segments).
// Fragment read: lane (fr=l&15, kg=l>>4) reads region (rowblk*2+ks2) byte fr*64+kg*16.
__global__ __launch_bounds__(256, 4) void gamma2_gemm(const __bf16* __restrict__ E,
                                                      const float* __restrict__ vn2v,
                                                      float* __restrict__ gamma2) {
  int bid = blockIdx.x, tid = threadIdx.x;
  int wid = tid >> 6, lane = tid & 63;
  int wr = wid >> 1, wc = wid & 1;

  // XCD-pinned decode (round-2): batch b = xcd>>1; E_b (4MB) ~ one XCD L2.
  int xcd = bid & 7, r = bid >> 3;
  int b = xcd >> 1;
  int tm = ((xcd & 1) << 3) | (r & 7);   // 0..15
  int tn = r >> 3;                        // 0..15

  __shared__ __bf16 As[2][4096], Bs[2][4096];
  char* AsB = (char*)As;
  char* BsB = (char*)Bs;

  const __bf16* Eb = E + (size_t)b * D3 * D2;
  // staging sources: region0 = wid, region1 = wid+4
  int rb0 = wid >> 1, ks0 = wid & 1;          // region wid
  int rb1 = (wid + 4) >> 1, ks1 = wid & 1;    // region wid+4  ((wid+4)&1 == wid&1)
  int srow = lane >> 2, skc = lane & 3;
  const __bf16* gA0 = Eb + (size_t)(tm * 64 + rb0 * 16 + srow) * D2 + ks0 * 32 + skc * 8;
  const __bf16* gA1 = Eb + (size_t)(tm * 64 + rb1 * 16 + srow) * D2 + ks1 * 32 + skc * 8;
  const __bf16* gB0 = Eb + (size_t)(tn * 64 + rb0 * 16 + srow) * D2 + ks0 * 32 + skc * 8;
  const __bf16* gB1 = Eb + (size_t)(tn * 64 + rb1 * 16 + srow) * D2 + ks1 * 32 + skc * 8;
  unsigned dst0 = (unsigned)wid * 1024u;          // HW adds lane*16
  unsigned dst1 = dst0 + 4096u;

  int fr = lane & 15, kg = lane >> 4;
  unsigned po = (unsigned)(fr * 64 + kg * 16);
  unsigned aM0 = (unsigned)(wr * 4096) + po;          // mi=0: + ks2*1024
  unsigned aM1 = aM0 + 2048u;                          // mi=1
  unsigned bN0 = (unsigned)(wc * 4096) + po;
  unsigned bN1 = bN0 + 2048u;

  f32x4 acc[2][2] = {};

#define STAGE(bufoff, kelem)                                   \
  {                                                            \
    GLOAD16(gA0 + (kelem), AsB + (bufoff) + dst0);             \
    GLOAD16(gA1 + (kelem), AsB + (bufoff) + dst1);             \
    GLOAD16(gB0 + (kelem), BsB + (bufoff) + dst0);             \
    GLOAD16(gB1 + (kelem), BsB + (bufoff) + dst1);             \
  }

#define COMPUTE(bufoff)                                                         \
  {                                                                             \
    _Pragma("unroll")                                                           \
    for (int ks2 = 0; ks2 < 2; ks2++) {                                         \
      unsigned kso = (unsigned)ks2 << 10;                                       \
      bf16x8 a0 = *(const bf16x8*)(AsB + (bufoff) + aM0 + kso);                 \
      bf16x8 a1 = *(const bf16x8*)(AsB + (bufoff) + aM1 + kso);                 \
      bf16x8 b0 = *(const bf16x8*)(BsB + (bufoff) + bN0 + kso);                 \
      bf16x8 b1 = *(const bf16x8*)(BsB + (bufoff) + bN1 + kso);                 \
      acc[0][0] = __builtin_amdgcn_mfma_f32_16x16x32_bf16(a0, b0, acc[0][0], 0, 0, 0); \
      acc[0][1] = __builtin_amdgcn_mfma_f32_16x16x32_bf16(a0, b1, acc[0][1], 0, 0, 0); \
      acc[1][0] = __builtin_amdgcn_mfma_f32_16x16x32_bf16(a1, b0, acc[1][0], 0, 0, 0); \
      acc[1][1] = __builtin_amdgcn_mfma_f32_16x16x32_bf16(a1, b1, acc[1][1], 0, 0, 0); \
    }                                                                           \
  }

  STAGE(0u, 0);
  __syncthreads();
  unsigned cur = 0;
  #pragma unroll 1
  for (int kt = 0; kt < 31; kt++) {
    unsigned nxt = cur ^ 8192u;
    STAGE(nxt, (kt + 1) * 64);   // prefetch next tile; latency hides under compute
    COMPUTE(cur);
    __syncthreads();             // vmcnt(0)+lgkmcnt(0)+barrier: next tile ready
    cur = nxt;
  }
  COMPUTE(cur);
#undef STAGE
#undef COMPUTE

  float vn2 = vn2v[b];
  float* outb = gamma2 + (size_t)b * D3 * D3;
  int row0 = tm * 64 + wr * 32 + kg * 4;
  int col0 = tn * 64 + wc * 32 + fr;
  #pragma unroll
  for (int mi = 0; mi < 2; mi++)
    #pragma unroll
    for (int ni = 0; ni < 2; ni++)
      #pragma unroll
      for (int rg = 0; rg < 4; rg++) {
        int row = row0 + mi * 16 + rg;
        int cc = col0 + ni * 16;
        float v = acc[mi][ni][rg];
        if (row == cc) v += vn2;
        outb[(size_t)row * D3 + cc] = v;
      }
}

extern "C" void kernel_launch(void* const* d_in, const int* in_sizes, int n_in,
                              void* d_out, int out_size, void* d_ws, size_t ws_size,
                              hipStream_t stream) {
  (void)in_sizes; (void)n_in; (void)out_size; (void)ws_size;
  const float* x    = (const float*)d_in[0];
  const float* bias = (const float*)d_in[1];
  const float* W1   = (const float*)d_in[2];
  const float* W2   = (const float*)d_in[3];
  const float* g1   = (const float*)d_in[4];
  const float* g2   = (const float*)d_in[5];
  float* out = (float*)d_out;

  float* ws     = (float*)d_ws;
  float* pooled = ws;                    // 4*3072
  float* musp   = pooled + 4 * D1;       // 4*2048
  float* dscale = musp + 4 * D2;         // 4*2048
  float* m2b    = dscale + 4 * D2;       // 4*2048
  float* Pp1    = m2b + 4 * D2;          // 4*2048
  float* Pp2    = Pp1 + 4 * D2;          // 4*1024
  float* Spart  = Pp2 + 4 * D3;          // 48
  float* vn2v   = Spart + 48;            // 4
  size_t used = (size_t)(4 * D1 + 4 * 4 * D2 + 4 * D3 + 64) * 4;
  size_t eoff = (used + 255) / 256 * 256;
  __bf16* E = (__bf16*)((char*)d_ws + eoff);   // 4*1024*2048 bf16 = 16 MiB

  float* mu2_out  = out;
  float* gam_out  = out + 4 * D3;
  float* ptot_out = out + 4 * D3 + (size_t)4 * D3 * D3;

  pool_kernel<<<48, 256, 0, stream>>>(x, bias, pooled, Spart);
  lin1_kernel<<<2048, 256, 0, stream>>>(pooled, W1, Spart, g1, musp, dscale, m2b, Pp1);
  lin2_prep_kernel<<<1024, 256, 0, stream>>>(W2, musp, dscale, m2b, E, mu2_out, Pp2);
  scalars_kernel<<<4, 256, 0, stream>>>(m2b, Pp1, Pp2, g1, g2, vn2v, ptot_out);
  gamma2_gemm<<<1024, 256, 0, stream>>>(E, vn2v, gam_out);
}

// Round 5
// 56.406 us; speedup vs baseline: 1.6017x; 1.0280x over previous
//
#include <hip/hip_runtime.h>
#include <hip/hip_bf16.h>
#include <cstdint>

#define SIGMA 0.01f

constexpr int D1 = 3072;
constexpr int D2 = 2048;
constexpr int D3 = 1024;

typedef __bf16 bf16x8 __attribute__((ext_vector_type(8)));
typedef float f32x4 __attribute__((ext_vector_type(4)));

#define GLOAD16(gp, lp) \
  __builtin_amdgcn_global_load_lds((const __attribute__((address_space(1))) void*)(gp), \
                                   (__attribute__((address_space(3))) void*)(lp), 16, 0, 0)

// ---------- K1: bias add + 2x2 avgpool + per-block partial sum(pooled^2) ----------
__global__ void pool_kernel(const float* __restrict__ x, const float* __restrict__ bias,
                            float* __restrict__ pooled, float* __restrict__ Spart) {
  int idx = blockIdx.x * 256 + threadIdx.x;   // [0, 4*3072)
  int b = idx / D1;
  int r = idx % D1;
  int c = r >> 10;
  int oh = (r >> 5) & 31;
  int ow = r & 31;
  int xb = ((b * 3 + c) * 64 + oh * 2) * 64 + ow * 2;
  int bb = (c * 64 + oh * 2) * 64 + ow * 2;
  float v = 0.25f * ((x[xb] + bias[bb]) + (x[xb + 1] + bias[bb + 1]) +
                     (x[xb + 64] + bias[bb + 64]) + (x[xb + 65] + bias[bb + 65]));
  pooled[idx] = v;
  float s = v * v;
  #pragma unroll
  for (int off = 32; off; off >>= 1) s += __shfl_down(s, off, 64);
  __shared__ float wsum[4];
  if ((threadIdx.x & 63) == 0) wsum[threadIdx.x >> 6] = s;
  __syncthreads();
  if (threadIdx.x == 0) Spart[blockIdx.x] = wsum[0] + wsum[1] + wsum[2] + wsum[3];
}

// ---------- K2: mu=pooled@W1^T (+activation moments), 2 rows/block ----------
__global__ void lin1_kernel(const float* __restrict__ pooled, const float* __restrict__ W1,
                            const float* __restrict__ Spart, const float* __restrict__ g1p,
                            float* __restrict__ musp, float* __restrict__ dscale,
                            float* __restrict__ m2b, float* __restrict__ Pp1) {
  int o2 = blockIdx.x << 1, tid = threadIdx.x;
  const float4* w0p = (const float4*)(W1 + (size_t)o2 * D1);
  const float4* w1p = (const float4*)(W1 + (size_t)(o2 + 1) * D1);
  const float4* p4 = (const float4*)pooled;
  float a0[4] = {0,0,0,0}, q0[4] = {0,0,0,0}, a1[4] = {0,0,0,0}, q1[4] = {0,0,0,0};
  #pragma unroll
  for (int it = 0; it < 3; it++) {
    int i4 = tid + it * 256;
    float4 w0 = w0p[i4], w1 = w1p[i4];
    float x0x = fabsf(w0.x), x0y = fabsf(w0.y), x0z = fabsf(w0.z), x0w = fabsf(w0.w);
    float x1x = fabsf(w1.x), x1y = fabsf(w1.y), x1z = fabsf(w1.z), x1w = fabsf(w1.w);
    #pragma unroll
    for (int b = 0; b < 4; b++) {
      float4 p = p4[b * 768 + i4];
      float px = p.x * p.x, py = p.y * p.y, pz = p.z * p.z, pw = p.w * p.w;
      a0[b] += w0.x * p.x + w0.y * p.y + w0.z * p.z + w0.w * p.w;
      q0[b] += x0x * px + x0y * py + x0z * pz + x0w * pw;
      a1[b] += w1.x * p.x + w1.y * p.y + w1.z * p.z + w1.w * p.w;
      q1[b] += x1x * px + x1y * py + x1z * pz + x1w * pw;
    }
  }
  __shared__ float red[16][4];
  #pragma unroll
  for (int v = 0; v < 16; v++) {
    float s = (v < 4) ? a0[v] : (v < 8) ? q0[v - 4] : (v < 12) ? a1[v - 8] : q1[v - 12];
    #pragma unroll
    for (int off = 32; off; off >>= 1) s += __shfl_down(s, off, 64);
    if ((tid & 63) == 0) red[v][tid >> 6] = s;
  }
  __syncthreads();
  if (tid < 16) {
    float s = red[tid][0] + red[tid][1] + red[tid][2] + red[tid][3];
    int rr = tid >> 3, u = tid & 7;
    int o = o2 + rr;
    if (u < 4) {
      int b = u;
      float ss = 0.f;
      #pragma unroll
      for (int i = 0; i < 12; i++) ss += Spart[b * 12 + i];
      float c1 = g1p[0];
      float vn1 = 2.0f * (SIGMA / c1) * (SIGMA / c1) * ss;
      float d = 1.0f / (1.0f + expf(-s));
      float sp = fmaxf(s, 0.f) + log1pf(expf(-fabsf(s)));
      musp[b * D2 + o] = sp;
      dscale[b * D2 + o] = sqrtf(vn1) * d;
      m2b[b * D2 + o] = sp * sp + vn1 * d * d;
    } else {
      Pp1[(size_t)(u - 4) * D2 + o] = s;
    }
  }
}

// ---------- K3: E = bf16(W2 * dscale); mu2 = musp @ W2^T; Pp2 partials (2 rows/block) ----------
__global__ void lin2_prep_kernel(const float* __restrict__ W2, const float* __restrict__ musp,
                                 const float* __restrict__ dscale, const float* __restrict__ m2b,
                                 __bf16* __restrict__ E, float* __restrict__ mu2,
                                 float* __restrict__ Pp2) {
  int o2 = blockIdx.x << 1, tid = threadIdx.x;
  int j0 = tid * 8;
  float w0[8], w1[8];
  *(float4*)&w0[0] = *(const float4*)(W2 + (size_t)o2 * D2 + j0);
  *(float4*)&w0[4] = *(const float4*)(W2 + (size_t)o2 * D2 + j0 + 4);
  *(float4*)&w1[0] = *(const float4*)(W2 + (size_t)(o2 + 1) * D2 + j0);
  *(float4*)&w1[4] = *(const float4*)(W2 + (size_t)(o2 + 1) * D2 + j0 + 4);
  float a0[4], q0[4], a1[4], q1[4];
  #pragma unroll
  for (int b = 0; b < 4; b++) {
    const float* ms = musp + b * D2 + j0;
    const float* dsc = dscale + b * D2 + j0;
    const float* mb = m2b + b * D2 + j0;
    bf16x8 e0, e1;
    float s0 = 0.f, p0 = 0.f, s1 = 0.f, p1 = 0.f;
    #pragma unroll
    for (int jj = 0; jj < 8; jj++) {
      float dv = dsc[jj], mv = ms[jj], bv = mb[jj];
      e0[jj] = (__bf16)(w0[jj] * dv);
      e1[jj] = (__bf16)(w1[jj] * dv);
      s0 += w0[jj] * mv;  p0 += fabsf(w0[jj]) * bv;
      s1 += w1[jj] * mv;  p1 += fabsf(w1[jj]) * bv;
    }
    *(bf16x8*)(E + ((size_t)b * D3 + o2) * D2 + j0) = e0;
    *(bf16x8*)(E + ((size_t)b * D3 + o2 + 1) * D2 + j0) = e1;
    a0[b] = s0; q0[b] = p0; a1[b] = s1; q1[b] = p1;
  }
  __shared__ float red[16][4];
  #pragma unroll
  for (int v = 0; v < 16; v++) {
    float s = (v < 4) ? a0[v] : (v < 8) ? q0[v - 4] : (v < 12) ? a1[v - 8] : q1[v - 12];
    #pragma unroll
    for (int off = 32; off; off >>= 1) s += __shfl_down(s, off, 64);
    if ((tid & 63) == 0) red[v][tid >> 6] = s;
  }
  __syncthreads();
  if (tid < 16) {
    float s = red[tid][0] + red[tid][1] + red[tid][2] + red[tid][3];
    int rr = tid >> 3, u = tid & 7;
    int o = o2 + rr;
    if (u < 4) mu2[u * D3 + o] = s;
    else Pp2[(size_t)(u - 4) * D3 + o] = s;
  }
}

// ---------- K4: per-batch scalars: vn2[b], Ptot[b] ----------
__global__ void scalars_kernel(const float* __restrict__ m2b, const float* __restrict__ Pp1,
                               const float* __restrict__ Pp2, const float* __restrict__ g1p,
                               const float* __restrict__ g2p, float* __restrict__ vn2v,
                               float* __restrict__ Ptot) {
  int b = blockIdx.x, tid = threadIdx.x;
  float sm = 0.f, s1 = 0.f, s2 = 0.f;
  #pragma unroll
  for (int i = 0; i < 8; i++) {
    sm += m2b[(size_t)b * D2 + tid + i * 256];
    s1 += Pp1[(size_t)b * D2 + tid + i * 256];
  }
  #pragma unroll
  for (int i = 0; i < 4; i++) s2 += Pp2[(size_t)b * D3 + tid + i * 256];
  __shared__ float red[3][4];
  #pragma unroll
  for (int v = 0; v < 3; v++) {
    float s = (v == 0) ? sm : (v == 1) ? s1 : s2;
    #pragma unroll
    for (int off = 32; off; off >>= 1) s += __shfl_down(s, off, 64);
    if ((tid & 63) == 0) red[v][tid >> 6] = s;
  }
  __syncthreads();
  if (tid == 0) {
    float c2 = g2p[0];
    float smt = red[0][0] + red[0][1] + red[0][2] + red[0][3];
    float s1t = red[1][0] + red[1][1] + red[1][2] + red[1][3];
    float s2t = red[2][0] + red[2][1] + red[2][2] + red[2][3];
    vn2v[b] = 2.0f * (SIGMA / c2) * (SIGMA / c2) * smt;
    Ptot[b] = g1p[0] * s1t + c2 * s2t;
  }
}

// ---------- K5: gamma2[b] = E_b E_b^T + vn2 I ----------
// Upper-triangular tiles only (136/batch, 544 blocks); mirror-write the lower half.
// 64x64 tiles, dbuf LDS, 2-phase prefetch (round-4 verified structure).
__global__ __launch_bounds__(256, 4) void gamma2_gemm(const __bf16* __restrict__ E,
                                                      const float* __restrict__ vn2v,
                                                      float* __restrict__ gamma2) {
  int bid = blockIdx.x, tid = threadIdx.x;
  int wid = tid >> 6, lane = tid & 63;
  int wr = wid >> 1, wc = wid & 1;

  // XCD-pinned decode: 544 blocks (544%8==0), batch b = xcd>>1.
  int xcd = bid & 7, r = bid >> 3;          // r in [0,68)
  int b = xcd >> 1;
  int t = (r << 1) | (xcd & 1);             // [0,136) tile id within batch
  // triangular decode: tiles (tm,tn) with tn>=tm
  int s = 135 - t;
  int k = (int)((sqrtf((float)(8 * s + 1)) - 1.0f) * 0.5f);
  while ((k + 1) * (k + 2) / 2 <= s) k++;
  while (k * (k + 1) / 2 > s) k--;
  int i = s - k * (k + 1) / 2;
  int tm = 15 - k, tn = 15 - i;

  __shared__ __bf16 As[2][4096], Bs[2][4096];
  char* AsB = (char*)As;
  char* BsB = (char*)Bs;

  const __bf16* Eb = E + (size_t)b * D3 * D2;
  int rb0 = wid >> 1, ks0 = wid & 1;          // region wid
  int rb1 = (wid + 4) >> 1;                   // region wid+4 (same k-half)
  int srow = lane >> 2, skc = lane & 3;
  const __bf16* gA0 = Eb + (size_t)(tm * 64 + rb0 * 16 + srow) * D2 + ks0 * 32 + skc * 8;
  const __bf16* gA1 = Eb + (size_t)(tm * 64 + rb1 * 16 + srow) * D2 + ks0 * 32 + skc * 8;
  const __bf16* gB0 = Eb + (size_t)(tn * 64 + rb0 * 16 + srow) * D2 + ks0 * 32 + skc * 8;
  const __bf16* gB1 = Eb + (size_t)(tn * 64 + rb1 * 16 + srow) * D2 + ks0 * 32 + skc * 8;
  unsigned dst0 = (unsigned)wid * 1024u;          // HW adds lane*16
  unsigned dst1 = dst0 + 4096u;

  int fr = lane & 15, kg = lane >> 4;
  unsigned po = (unsigned)(fr * 64 + kg * 16);
  unsigned aM0 = (unsigned)(wr * 4096) + po;
  unsigned aM1 = aM0 + 2048u;
  unsigned bN0 = (unsigned)(wc * 4096) + po;
  unsigned bN1 = bN0 + 2048u;

  f32x4 acc[2][2] = {};

#define STAGE(bufoff, kelem)                                   \
  {                                                            \
    GLOAD16(gA0 + (kelem), AsB + (bufoff) + dst0);             \
    GLOAD16(gA1 + (kelem), AsB + (bufoff) + dst1);             \
    GLOAD16(gB0 + (kelem), BsB + (bufoff) + dst0);             \
    GLOAD16(gB1 + (kelem), BsB + (bufoff) + dst1);             \
  }

#define COMPUTE(bufoff)                                                         \
  {                                                                             \
    _Pragma("unroll")                                                           \
    for (int ks2 = 0; ks2 < 2; ks2++) {                                         \
      unsigned kso = (unsigned)ks2 << 10;                                       \
      bf16x8 a0 = *(const bf16x8*)(AsB + (bufoff) + aM0 + kso);                 \
      bf16x8 a1 = *(const bf16x8*)(AsB + (bufoff) + aM1 + kso);                 \
      bf16x8 b0 = *(const bf16x8*)(BsB + (bufoff) + bN0 + kso);                 \
      bf16x8 b1 = *(const bf16x8*)(BsB + (bufoff) + bN1 + kso);                 \
      acc[0][0] = __builtin_amdgcn_mfma_f32_16x16x32_bf16(a0, b0, acc[0][0], 0, 0, 0); \
      acc[0][1] = __builtin_amdgcn_mfma_f32_16x16x32_bf16(a0, b1, acc[0][1], 0, 0, 0); \
      acc[1][0] = __builtin_amdgcn_mfma_f32_16x16x32_bf16(a1, b0, acc[1][0], 0, 0, 0); \
      acc[1][1] = __builtin_amdgcn_mfma_f32_16x16x32_bf16(a1, b1, acc[1][1], 0, 0, 0); \
    }                                                                           \
  }

  STAGE(0u, 0);
  __syncthreads();
  unsigned cur = 0;
  #pragma unroll 1
  for (int kt = 0; kt < 31; kt++) {
    unsigned nxt = cur ^ 8192u;
    STAGE(nxt, (kt + 1) * 64);   // prefetch next tile; latency hides under compute
    COMPUTE(cur);
    __syncthreads();
    cur = nxt;
  }
  COMPUTE(cur);
#undef STAGE
#undef COMPUTE

  float vn2 = vn2v[b];
  float* outb = gamma2 + (size_t)b * D3 * D3;
  int row0 = tm * 64 + wr * 32 + kg * 4;
  int col0 = tn * 64 + wc * 32 + fr;
  #pragma unroll
  for (int mi = 0; mi < 2; mi++)
    #pragma unroll
    for (int ni = 0; ni < 2; ni++)
      #pragma unroll
      for (int rg = 0; rg < 4; rg++) {
        int row = row0 + mi * 16 + rg;
        int cc = col0 + ni * 16;
        float v = acc[mi][ni][rg];
        if (row == cc) v += vn2;
        outb[(size_t)row * D3 + cc] = v;
      }
  if (tm != tn) {
    // mirror: acc[mi][ni][0..3] are rows row0+mi*16.. at col cc -> 4 consecutive
    // floats in mirrored row cc starting at col row0+mi*16 (16B-aligned).
    #pragma unroll
    for (int mi = 0; mi < 2; mi++)
      #pragma unroll
      for (int ni = 0; ni < 2; ni++) {
        int cc = col0 + ni * 16;
        int rowb = row0 + mi * 16;
        *(f32x4*)(outb + (size_t)cc * D3 + rowb) = acc[mi][ni];
      }
  }
}

extern "C" void kernel_launch(void* const* d_in, const int* in_sizes, int n_in,
                              void* d_out, int out_size, void* d_ws, size_t ws_size,
                              hipStream_t stream) {
  (void)in_sizes; (void)n_in; (void)out_size; (void)ws_size;
  const float* x    = (const float*)d_in[0];
  const float* bias = (const float*)d_in[1];
  const float* W1   = (const float*)d_in[2];
  const float* W2   = (const float*)d_in[3];
  const float* g1   = (const float*)d_in[4];
  const float* g2   = (const float*)d_in[5];
  float* out = (float*)d_out;

  float* ws     = (float*)d_ws;
  float* pooled = ws;                    // 4*3072
  float* musp   = pooled + 4 * D1;       // 4*2048
  float* dscale = musp + 4 * D2;         // 4*2048
  float* m2b    = dscale + 4 * D2;       // 4*2048
  float* Pp1    = m2b + 4 * D2;          // 4*2048
  float* Pp2    = Pp1 + 4 * D2;          // 4*1024
  float* Spart  = Pp2 + 4 * D3;          // 48
  float* vn2v   = Spart + 48;            // 4
  size_t used = (size_t)(4 * D1 + 4 * 4 * D2 + 4 * D3 + 64) * 4;
  size_t eoff = (used + 255) / 256 * 256;
  __bf16* E = (__bf16*)((char*)d_ws + eoff);   // 4*1024*2048 bf16 = 16 MiB

  float* mu2_out  = out;
  float* gam_out  = out + 4 * D3;
  float* ptot_out = out + 4 * D3 + (size_t)4 * D3 * D3;

  pool_kernel<<<48, 256, 0, stream>>>(x, bias, pooled, Spart);
  lin1_kernel<<<1024, 256, 0, stream>>>(pooled, W1, Spart, g1, musp, dscale, m2b, Pp1);
  lin2_prep_kernel<<<512, 256, 0, stream>>>(W2, musp, dscale, m2b, E, mu2_out, Pp2);
  scalars_kernel<<<4, 256, 0, stream>>>(m2b, Pp1, Pp2, g1, g2, vn2v, ptot_out);
  gamma2_gemm<<<544, 256, 0, stream>>>(E, vn2v, gam_out);
}